// Round 17
// baseline (59.358 us; speedup 1.0000x reference)
//
#include <hip/hip_runtime.h>

#define INP (128*128*64)   // 1048576
#define NB 8
#define NBLK2 2048         // k_sample blocks per batch: (INP/2)/256
#define ZCAP 4
#define YCAP 16

typedef __attribute__((ext_vector_type(4))) float f32x4;
typedef __attribute__((ext_vector_type(2))) float f32x2;
typedef __attribute__((ext_vector_type(4))) unsigned int u32x4;
typedef int v4i __attribute__((ext_vector_type(4)));

#if __has_builtin(__builtin_amdgcn_make_buffer_rsrc) && __has_builtin(__builtin_amdgcn_raw_buffer_load_b32)
#define RSRC_T __amdgpu_buffer_rsrc_t
__device__ __forceinline__ RSRC_T make_rsrc(const float* p) {
    return __builtin_amdgcn_make_buffer_rsrc((void*)p, (short)0, INP * 4, 0x00020000);
}
__device__ __forceinline__ float bload(RSRC_T r, int boff) {
    return __builtin_bit_cast(float, __builtin_amdgcn_raw_buffer_load_b32(r, boff, 0, 0));
}
#else
#define RSRC_T v4i
__device__ __forceinline__ RSRC_T make_rsrc(const float* p) {
    union { const float* p; unsigned u[2]; } pun; pun.p = p;
    RSRC_T r;
    r.x = (int)pun.u[0]; r.y = (int)pun.u[1]; r.z = INP * 4; r.w = 0x00020000;
    return r;
}
__device__ __forceinline__ float bload(RSRC_T r, int boff) {
    return __builtin_amdgcn_raw_buffer_load_f32(r, boff, 0, 0);
}
#endif

#if __has_builtin(__builtin_amdgcn_raw_buffer_load_b64)
__device__ __forceinline__ f32x2 bload2(RSRC_T r, int boff) {
    return __builtin_bit_cast(f32x2, __builtin_amdgcn_raw_buffer_load_b64(r, boff, 0, 0));
}
#else
__device__ __forceinline__ f32x2 bload2(RSRC_T r, int boff) {
    f32x2 v; v.x = bload(r, boff); v.y = bload(r, boff + 4); return v;
}
#endif

#if __has_builtin(__builtin_amdgcn_raw_buffer_load_b128)
__device__ __forceinline__ f32x4 bload4(RSRC_T r, int boff) {
    return __builtin_bit_cast(f32x4, __builtin_amdgcn_raw_buffer_load_b128(r, boff, 0, 0));
}
#else
__device__ __forceinline__ f32x4 bload4(RSRC_T r, int boff) {
    f32x2 a = bload2(r, boff), b = bload2(r, boff + 8);
    f32x4 v; v.x = a.x; v.y = a.y; v.z = b.x; v.w = b.y; return v;
}
#endif

__device__ __forceinline__ float wave_reduce(float v) {
    #pragma unroll
    for (int off = 32; off > 0; off >>= 1) v += __shfl_down(v, off, 64);
    return v;
}
__device__ __forceinline__ int wave_rmin(int v) {
    #pragma unroll
    for (int off = 32; off > 0; off >>= 1) v = min(v, __shfl_down(v, off, 64));
    return v;
}
__device__ __forceinline__ int wave_rmax(int v) {
    #pragma unroll
    for (int off = 32; off > 0; off >>= 1) v = max(v, __shfl_down(v, off, 64));
    return v;
}

// R13-proven fallback prep (clamped offsets + weight-resolved x edges).
struct Prep {
    int o[4];
    float wa, wb, wy0, wy1, wz0, wz1;
};

__device__ __forceinline__ Prep prep_s(float ix, float iy, float iz) {
    const float fx = floorf(ix), fy = floorf(iy), fz = floorf(iz);
    const int x0 = (int)fx, y0 = (int)fy, z0 = (int)fz;
    const int x1 = x0 + 1,  y1 = y0 + 1,  z1 = z0 + 1;

    const float wx1 = ix - fx, wx0 = 1.f - wx1;
    Prep p;
    p.wy1 = iy - fy; p.wy0 = 1.f - p.wy1;
    p.wz1 = iz - fz; p.wz0 = 1.f - p.wz1;
    p.wy0 = ((unsigned)y0 < 128u) ? p.wy0 : 0.f;
    p.wy1 = ((unsigned)y1 < 128u) ? p.wy1 : 0.f;
    p.wz0 = ((unsigned)z0 < 128u) ? p.wz0 : 0.f;
    p.wz1 = ((unsigned)z1 < 128u) ? p.wz1 : 0.f;

    const float wx0z = ((unsigned)x0 < 64u) ? wx0 : 0.f;
    const float wx1z = ((unsigned)x1 < 64u) ? wx1 : 0.f;
    const bool hi = (x0 >= 63);
    const bool lo = (x0 < 0);
    p.wa = lo ? wx1z : (hi ? 0.f : wx0z);
    p.wb = hi ? wx0z : (lo ? 0.f : wx1z);

    const int yc0 = min(max(y0, 0), 127), yc1 = min(max(y1, 0), 127);
    const int zc0 = min(max(z0, 0), 127), zc1 = min(max(z1, 0), 127);
    const int xpb = min(max(x0, 0), 62) << 2;
    const int yb0 = (yc0 << 8) + xpb, yb1 = (yc1 << 8) + xpb;
    const int zb0 = zc0 << 15,        zb1 = zc1 << 15;
    p.o[0] = zb0 + yb0; p.o[1] = zb0 + yb1;
    p.o[2] = zb1 + yb0; p.o[3] = zb1 + yb1;
    return p;
}

__device__ __forceinline__ float blend_s(const Prep& p, const f32x2 v[4]) {
    const float bx00 = fmaf(p.wb, v[0].y, p.wa * v[0].x);
    const float bx01 = fmaf(p.wb, v[1].y, p.wa * v[1].x);
    const float bx10 = fmaf(p.wb, v[2].y, p.wa * v[2].x);
    const float bx11 = fmaf(p.wb, v[3].y, p.wa * v[3].x);
    const float by0  = fmaf(p.wy1, bx01, p.wy0 * bx00);
    const float by1  = fmaf(p.wy1, bx11, p.wy0 * bx10);
    return fmaf(p.wz1, by1, p.wz0 * by0);
}

// LDS-path sample: weights identical to prep_s; values come from the staged
// slab. Slot (z',y') holds volume row (clamp(zorg+z'), clamp(yorg+y')), so
// reading slot (z0-zorg, y0-yorg) yields exactly the clamped-row value the
// R13 gather used; y/z weight zeroing annihilates invalid planes; x edges
// resolved in (wa,wb) as proven.
__device__ __forceinline__ float sample_lds(const float* __restrict__ slab,
                                            float ix, float iy, float iz,
                                            int zorg, int yorg) {
    const float fx = floorf(ix), fy = floorf(iy), fz = floorf(iz);
    const int x0 = (int)fx, y0 = (int)fy, z0 = (int)fz;

    const float wx1 = ix - fx, wx0 = 1.f - wx1;
    float wy1 = iy - fy, wy0 = 1.f - wy1;
    float wz1 = iz - fz, wz0 = 1.f - wz1;
    wy0 = ((unsigned)y0       < 128u) ? wy0 : 0.f;
    wy1 = ((unsigned)(y0 + 1) < 128u) ? wy1 : 0.f;
    wz0 = ((unsigned)z0       < 128u) ? wz0 : 0.f;
    wz1 = ((unsigned)(z0 + 1) < 128u) ? wz1 : 0.f;

    const float wx0z = ((unsigned)x0 < 64u) ? wx0 : 0.f;
    const float wx1z = ((unsigned)(x0 + 1) < 64u) ? wx1 : 0.f;
    const bool hi = (x0 >= 63);
    const bool lo = (x0 < 0);
    const float wa = lo ? wx1z : (hi ? 0.f : wx0z);
    const float wb = hi ? wx0z : (lo ? 0.f : wx1z);

    const int xp = min(max(x0, 0), 62);
    const int base = ((z0 - zorg) << 10) + ((y0 - yorg) << 6) + xp;

    const float v000 = slab[base],        v001 = slab[base + 1];
    const float v010 = slab[base + 64],   v011 = slab[base + 65];
    const float v100 = slab[base + 1024], v101 = slab[base + 1025];
    const float v110 = slab[base + 1088], v111 = slab[base + 1089];

    const float bx00 = fmaf(wb, v001, wa * v000);
    const float bx01 = fmaf(wb, v011, wa * v010);
    const float bx10 = fmaf(wb, v101, wa * v100);
    const float bx11 = fmaf(wb, v111, wa * v110);
    const float by0  = fmaf(wy1, bx01, wy0 * bx00);
    const float by1  = fmaf(wy1, bx11, wy0 * bx10);
    return fmaf(wz1, by1, wz0 * by0);
}

// ---------------------------------------------------------------------------
// K1: one thread = TWO x-adjacent voxels (R12/R13-proven shape). NEW: the 8
// divergent pair-gathers are replaced by a dynamically-bounded LDS slab
// (<=4 z x 16 y x 64 x floats, 16KB) staged with 4 coalesced dwordx4/thread;
// corner reads become ds_read2_b32 (2-way bank alias = free). Block-uniform
// fallback to the R13 global-gather path if spans exceed capacity.
// ---------------------------------------------------------------------------
__global__ __launch_bounds__(256) void k_sample(
    const float* __restrict__ x, const int* __restrict__ r_index,
    const float* __restrict__ theta, const float* __restrict__ lnw,
    float* __restrict__ x_reg, float* __restrict__ partial)
{
    __shared__ float slab[ZCAP * YCAP * 64];   // 16 KB
    __shared__ int   red[4][4];                // per-wave {minz,maxz,miny,maxy}
    __shared__ int   bnd[3];                   // zorg, yorg, ok-flag
    __shared__ float smt[4];

    const int b   = blockIdx.y;
    const int tid = threadIdx.x;
    const int i2  = blockIdx.x * 256 + tid;    // pair index
    const int w0  = (i2 & 31) << 1;            // w of voxel 0
    const int h   = (i2 >> 5) & 127;
    const int d   = i2 >> 12;

    const f32x2 w2 = ((const f32x2*)lnw)[i2];  // issue early

    const float xs = fmaf((float)w0, 1.f/32.f, 1.f/64.f  - 1.f);
    const float ys = fmaf((float)h,  1.f/64.f, 1.f/128.f - 1.f);
    const float zs = fmaf((float)d,  1.f/64.f, 1.f/128.f - 1.f);

    const float* __restrict__ t = theta + r_index[b] * 12;   // uniform
    const float gx = fmaf(t[0], xs, fmaf(t[1], ys, fmaf(t[2],  zs, t[3])));
    const float gy = fmaf(t[4], xs, fmaf(t[5], ys, fmaf(t[6],  zs, t[7])));
    const float gz = fmaf(t[8], xs, fmaf(t[9], ys, fmaf(t[10], zs, t[11])));
    const float ix0 = fmaf(gx, 32.f, 31.5f);
    const float iy0 = fmaf(gy, 64.f, 63.5f);
    const float iz0 = fmaf(gz, 64.f, 63.5f);
    const float ix1 = ix0 + t[0];
    const float iy1 = iy0 + 2.f * t[4];
    const float iz1 = iz0 + 2.f * t[8];

    // block bounds of needed rows
    const int y00 = (int)floorf(iy0), z00 = (int)floorf(iz0);
    const int y10 = (int)floorf(iy1), z10 = (int)floorf(iz1);
    int mnz = wave_rmin(min(z00, z10));
    int mxz = wave_rmax(max(z00, z10));
    int mny = wave_rmin(min(y00, y10));
    int mxy = wave_rmax(max(y00, y10));
    if ((tid & 63) == 0) {
        red[tid >> 6][0] = mnz; red[tid >> 6][1] = mxz;
        red[tid >> 6][2] = mny; red[tid >> 6][3] = mxy;
    }
    __syncthreads();
    if (tid == 0) {
        int a0 = min(min(red[0][0], red[1][0]), min(red[2][0], red[3][0]));
        int a1 = max(max(red[0][1], red[1][1]), max(red[2][1], red[3][1]));
        int a2 = min(min(red[0][2], red[1][2]), min(red[2][2], red[3][2]));
        int a3 = max(max(red[0][3], red[1][3]), max(red[2][3], red[3][3]));
        bnd[0] = a0; bnd[1] = a2;
        bnd[2] = ((a1 - a0 + 2) <= ZCAP) & ((a3 - a2 + 2) <= YCAP);
    }
    __syncthreads();
    const int zorg = bnd[0], yorg = bnd[1], ok = bnd[2];

    const RSRC_T r = make_rsrc(x + (size_t)b * INP);
    float o0, o1;

    if (ok) {
        // stage: 64 rows (z' = r>>4, y' = r&15), each thread 16 floats
        const int row = tid >> 2, part = tid & 3;
        const int gzr = min(max(zorg + (row >> 4), 0), 127);
        const int gyr = min(max(yorg + (row & 15), 0), 127);
        const int src = (gzr << 15) + (gyr << 8) + (part << 6);
        float* dst = slab + (row << 6) + (part << 4);
        #pragma unroll
        for (int k = 0; k < 4; ++k) {
            const f32x4 v = bload4(r, src + k * 16);
            *(f32x4*)(dst + k * 4) = v;
        }
        __syncthreads();
        o0 = sample_lds(slab, ix0, iy0, iz0, zorg, yorg);
        o1 = sample_lds(slab, ix1, iy1, iz1, zorg, yorg);
    } else {
        // R13-proven global-gather fallback (block-uniform branch)
        const Prep p0 = prep_s(ix0, iy0, iz0);
        const Prep p1 = prep_s(ix1, iy1, iz1);
        f32x2 v0[4], v1[4];
        #pragma unroll
        for (int j = 0; j < 4; ++j) v0[j] = bload2(r, p0.o[j]);
        #pragma unroll
        for (int j = 0; j < 4; ++j) v1[j] = bload2(r, p1.o[j]);
        o0 = blend_s(p0, v0);
        o1 = blend_s(p1, v1);
    }

    f32x2 o; o.x = o0; o.y = o1;
    __builtin_nontemporal_store(o, (f32x2*)(x_reg + (size_t)b * INP) + i2);

    // R5-proven tail: wave shfl reduce -> LDS combine -> ONE store per block
    float acc = fmaf(o1, w2.y, o0 * w2.x);
    acc = wave_reduce(acc);
    if ((tid & 63) == 0) smt[tid >> 6] = acc;
    __syncthreads();
    if (tid == 0)
        partial[b * NBLK2 + blockIdx.x] = smt[0] + smt[1] + smt[2] + smt[3];
}

// ---------------------------------------------------------------------------
// K2 (fused reduce+outer, R13-proven): grid (128 chunks, 8 batches).
// ---------------------------------------------------------------------------
__global__ __launch_bounds__(256) void k_outer(
    const float* __restrict__ lnw, const float* __restrict__ partial,
    float* __restrict__ L)
{
    const int b   = blockIdx.y;
    const int tid = threadIdx.x;

    const f32x4* p4 = (const f32x4*)(partial + b * NBLK2);   // 512 f32x4
    const f32x4 a0 = p4[tid];
    const f32x4 a1 = p4[tid + 256];
    float v = (a0.x + a0.y) + (a0.z + a0.w) + (a1.x + a1.y) + (a1.z + a1.w);
    v = wave_reduce(v);
    __shared__ float sm[4];
    __shared__ float smt;
    if ((tid & 63) == 0) sm[tid >> 6] = v;
    __syncthreads();
    if (tid == 0) smt = (sm[0] + sm[1]) + (sm[2] + sm[3]);
    __syncthreads();
    const float sb = smt;

    const int base = blockIdx.x * 2048 + tid;    // f32x4 units within batch
    const f32x4* w4p = (const f32x4*)lnw;
    f32x4* L4 = (f32x4*)L + (size_t)b * (INP / 4);
    #pragma unroll
    for (int k = 0; k < 8; ++k) {
        const f32x4 w4 = w4p[base + k * 256];
        __builtin_nontemporal_store(sb * w4, L4 + base + k * 256);
    }
}

extern "C" void kernel_launch(void* const* d_in, const int* in_sizes, int n_in,
                              void* d_out, int out_size, void* d_ws, size_t ws_size,
                              hipStream_t stream) {
    const float* x       = (const float*)d_in[0];
    const int*   r_index = (const int*)d_in[1];
    const float* theta   = (const float*)d_in[2];
    const float* lnw     = (const float*)d_in[3];

    float* x_reg = (float*)d_out;
    float* L     = (float*)d_out + (size_t)NB * INP;

    float* partial = (float*)d_ws;            // 8*2048 floats = 64 KB

    dim3 grid1(NBLK2, NB);
    k_sample<<<grid1, 256, 0, stream>>>(x, r_index, theta, lnw, x_reg, partial);
    dim3 grid2(128, NB);
    k_outer<<<grid2, 256, 0, stream>>>(lnw, partial, L);
}

// Round 18
// 34.990 us; speedup vs baseline: 1.6964x; 1.6964x over previous
//
#include <hip/hip_runtime.h>

#define INP (128*128*64)   // 1048576
#define NB 8
#define NBLK2 2048         // k_sample blocks per batch: (INP/2)/256

typedef __attribute__((ext_vector_type(4))) float f32x4;
typedef __attribute__((ext_vector_type(2))) float f32x2;
typedef int v4i __attribute__((ext_vector_type(4)));

#if __has_builtin(__builtin_amdgcn_make_buffer_rsrc) && __has_builtin(__builtin_amdgcn_raw_buffer_load_b32)
#define RSRC_T __amdgpu_buffer_rsrc_t
__device__ __forceinline__ RSRC_T make_rsrc(const float* p) {
    return __builtin_amdgcn_make_buffer_rsrc((void*)p, (short)0, INP * 4, 0x00020000);
}
__device__ __forceinline__ float bload(RSRC_T r, int boff) {
    return __builtin_bit_cast(float, __builtin_amdgcn_raw_buffer_load_b32(r, boff, 0, 0));
}
#else
#define RSRC_T v4i
__device__ __forceinline__ RSRC_T make_rsrc(const float* p) {
    union { const float* p; unsigned u[2]; } pun; pun.p = p;
    RSRC_T r;
    r.x = (int)pun.u[0]; r.y = (int)pun.u[1]; r.z = INP * 4; r.w = 0x00020000;
    return r;
}
__device__ __forceinline__ float bload(RSRC_T r, int boff) {
    return __builtin_amdgcn_raw_buffer_load_f32(r, boff, 0, 0);
}
#endif

#if __has_builtin(__builtin_amdgcn_raw_buffer_load_b64)
__device__ __forceinline__ f32x2 bload2(RSRC_T r, int boff) {
    return __builtin_bit_cast(f32x2, __builtin_amdgcn_raw_buffer_load_b64(r, boff, 0, 0));
}
#else
__device__ __forceinline__ f32x2 bload2(RSRC_T r, int boff) {
    f32x2 v; v.x = bload(r, boff); v.y = bload(r, boff + 4); return v;
}
#endif

#if __has_builtin(__builtin_amdgcn_raw_buffer_load_b128)
__device__ __forceinline__ f32x4 bload4(RSRC_T r, int boff) {
    return __builtin_bit_cast(f32x4, __builtin_amdgcn_raw_buffer_load_b128(r, boff, 0, 0));
}
#else
__device__ __forceinline__ f32x4 bload4(RSRC_T r, int boff) {
    f32x2 a = bload2(r, boff), b = bload2(r, boff + 8);
    f32x4 v; v.x = a.x; v.y = a.y; v.z = b.x; v.w = b.y; return v;
}
#endif

__device__ __forceinline__ float wave_reduce(float v) {
    #pragma unroll
    for (int off = 32; off > 0; off >>= 1) v += __shfl_down(v, off, 64);
    return v;
}

// R13-proven per-voxel gather prep (fallback path for row-mismatch lanes).
struct Prep {
    int o[4];
    float wa, wb, wy0, wy1, wz0, wz1;
};

__device__ __forceinline__ Prep prep_s(float ix, float iy, float iz) {
    const float fx = floorf(ix), fy = floorf(iy), fz = floorf(iz);
    const int x0 = (int)fx, y0 = (int)fy, z0 = (int)fz;
    const int x1 = x0 + 1,  y1 = y0 + 1,  z1 = z0 + 1;

    const float wx1 = ix - fx, wx0 = 1.f - wx1;
    Prep p;
    p.wy1 = iy - fy; p.wy0 = 1.f - p.wy1;
    p.wz1 = iz - fz; p.wz0 = 1.f - p.wz1;
    p.wy0 = ((unsigned)y0 < 128u) ? p.wy0 : 0.f;
    p.wy1 = ((unsigned)y1 < 128u) ? p.wy1 : 0.f;
    p.wz0 = ((unsigned)z0 < 128u) ? p.wz0 : 0.f;
    p.wz1 = ((unsigned)z1 < 128u) ? p.wz1 : 0.f;

    const float wx0z = ((unsigned)x0 < 64u) ? wx0 : 0.f;
    const float wx1z = ((unsigned)x1 < 64u) ? wx1 : 0.f;
    const bool hi = (x0 >= 63);
    const bool lo = (x0 < 0);
    p.wa = lo ? wx1z : (hi ? 0.f : wx0z);
    p.wb = hi ? wx0z : (lo ? 0.f : wx1z);

    const int yc0 = min(max(y0, 0), 127), yc1 = min(max(y1, 0), 127);
    const int zc0 = min(max(z0, 0), 127), zc1 = min(max(z1, 0), 127);
    const int xpb = min(max(x0, 0), 62) << 2;
    const int yb0 = (yc0 << 8) + xpb, yb1 = (yc1 << 8) + xpb;
    const int zb0 = zc0 << 15,        zb1 = zc1 << 15;
    p.o[0] = zb0 + yb0; p.o[1] = zb0 + yb1;
    p.o[2] = zb1 + yb0; p.o[3] = zb1 + yb1;
    return p;
}

__device__ __forceinline__ float blend_s(const Prep& p, const f32x2 v[4]) {
    const float bx00 = fmaf(p.wb, v[0].y, p.wa * v[0].x);
    const float bx01 = fmaf(p.wb, v[1].y, p.wa * v[1].x);
    const float bx10 = fmaf(p.wb, v[2].y, p.wa * v[2].x);
    const float bx11 = fmaf(p.wb, v[3].y, p.wa * v[3].x);
    const float by0  = fmaf(p.wy1, bx01, p.wy0 * bx00);
    const float by1  = fmaf(p.wy1, bx11, p.wy0 * bx10);
    return fmaf(p.wz1, by1, p.wz0 * by0);
}

// Build the 4-wide x-weight vector over window [xq, xq+3]:
// c[idx] = wa, c[idx+1] = wb (idx in {0,1,2} guaranteed), from the R13
// weight-resolution: interior (wa,wb)=(wx0,wx1); x0=63: (0,wx0) on pair
// (x[62],x[63]); x0=-1: (wx1,0) on pair (x[0],x[1]); |x0| beyond: (0,0).
__device__ __forceinline__ f32x4 xweights(float ix, int x0, int xq) {
    const float wx1 = ix - floorf(ix), wx0 = 1.f - wx1;
    const float wx0z = ((unsigned)x0 < 64u) ? wx0 : 0.f;
    const float wx1z = ((unsigned)(x0 + 1) < 64u) ? wx1 : 0.f;
    const bool hi = (x0 >= 63);
    const bool lo = (x0 < 0);
    const float wa = lo ? wx1z : (hi ? 0.f : wx0z);
    const float wb = hi ? wx0z : (lo ? 0.f : wx1z);
    const int idx = min(max(x0, 0), 62) - xq;   // 0..2
    f32x4 c;
    c.x = (idx == 0) ? wa : 0.f;
    c.y = (idx == 0) ? wb : ((idx == 1) ? wa : 0.f);
    c.z = (idx == 2) ? wa : ((idx == 1) ? wb : 0.f);
    c.w = (idx == 2) ? wb : 0.f;
    return c;
}

__device__ __forceinline__ float dot4(f32x4 c, f32x4 w) {
    return fmaf(c.x, w.x, c.y * w.y) + fmaf(c.z, w.z, c.w * w.w);
}

// ---------------------------------------------------------------------------
// K1: one thread = TWO x-adjacent voxels. NEW (R10-style instr halving):
// both voxels share the same 4 (y,z) rows whenever no y/z frac-crossing
// (~96%/lane); load ONE dwordx4 x-window [xq,xq+3] per row (4 VMEM instead
// of 8) and extract each voxel with a 4-wide weight vector. v1 falls back
// per-lane to the R13-proven prep_s gather when its rows differ or t0 is
// wild (x0'-x0 not in {0,1,2}). All offsets in-bounds (R3/R7 rule).
// ---------------------------------------------------------------------------
__global__ __launch_bounds__(256) void k_sample(
    const float* __restrict__ x, const int* __restrict__ r_index,
    const float* __restrict__ theta, const float* __restrict__ lnw,
    float* __restrict__ x_reg, float* __restrict__ partial)
{
    const int b  = blockIdx.y;
    const int i2 = blockIdx.x * 256 + threadIdx.x;   // pair index
    const int w0 = (i2 & 31) << 1;                   // w of voxel 0
    const int h  = (i2 >> 5) & 127;
    const int d  = i2 >> 12;

    const f32x2 w2 = ((const f32x2*)lnw)[i2];        // issue early

    const float xs = fmaf((float)w0, 1.f/32.f, 1.f/64.f  - 1.f);
    const float ys = fmaf((float)h,  1.f/64.f, 1.f/128.f - 1.f);
    const float zs = fmaf((float)d,  1.f/64.f, 1.f/128.f - 1.f);

    const float* __restrict__ t = theta + r_index[b] * 12;   // uniform
    const float gx = fmaf(t[0], xs, fmaf(t[1], ys, fmaf(t[2],  zs, t[3])));
    const float gy = fmaf(t[4], xs, fmaf(t[5], ys, fmaf(t[6],  zs, t[7])));
    const float gz = fmaf(t[8], xs, fmaf(t[9], ys, fmaf(t[10], zs, t[11])));
    const float ix0 = fmaf(gx, 32.f, 31.5f);
    const float iy0 = fmaf(gy, 64.f, 63.5f);
    const float iz0 = fmaf(gz, 64.f, 63.5f);
    const float ix1 = ix0 + t[0];
    const float iy1 = iy0 + 2.f * t[4];
    const float iz1 = iz0 + 2.f * t[8];

    const float fy0 = floorf(iy0), fz0 = floorf(iz0);
    const int x00 = (int)floorf(ix0);
    const int y00 = (int)fy0, z00 = (int)fz0;
    const int x10 = (int)floorf(ix1);
    const int y10 = (int)floorf(iy1), z10 = (int)floorf(iz1);

    // v0 y/z weights with zeroing (R13-proven semantics)
    float wy1 = iy0 - fy0, wy0 = 1.f - wy1;
    float wz1 = iz0 - fz0, wz0 = 1.f - wz1;
    wy0 = ((unsigned)y00       < 128u) ? wy0 : 0.f;
    wy1 = ((unsigned)(y00 + 1) < 128u) ? wy1 : 0.f;
    wz0 = ((unsigned)z00       < 128u) ? wz0 : 0.f;
    wz1 = ((unsigned)(z00 + 1) < 128u) ? wz1 : 0.f;

    // window row bases (clamped, in-bounds, non-negative)
    const int yc0 = min(max(y00, 0), 127), yc1 = min(max(y00 + 1, 0), 127);
    const int zc0 = min(max(z00, 0), 127), zc1 = min(max(z00 + 1, 0), 127);
    const int xq  = min(max(x00, 0), 60);
    const int xqb = xq << 2;
    const int yb0 = (yc0 << 8) + xqb, yb1 = (yc1 << 8) + xqb;
    const int zb0 = zc0 << 15,        zb1 = zc1 << 15;

    const RSRC_T r = make_rsrc(x + (size_t)b * INP);
    const f32x4 W00 = bload4(r, zb0 + yb0);   // row (y0,z0): x[xq..xq+3]
    const f32x4 W01 = bload4(r, zb0 + yb1);   // row (y1,z0)
    const f32x4 W10 = bload4(r, zb1 + yb0);   // row (y0,z1)
    const f32x4 W11 = bload4(r, zb1 + yb1);   // row (y1,z1)

    // v0 from window
    const f32x4 c0 = xweights(ix0, x00, xq);
    const float a00 = dot4(c0, W00), a01 = dot4(c0, W01);
    const float a10 = dot4(c0, W10), a11 = dot4(c0, W11);
    const float by0_0 = fmaf(wy1, a01, wy0 * a00);
    const float by1_0 = fmaf(wy1, a11, wy0 * a10);
    const float o0 = fmaf(wz1, by1_0, wz0 * by0_0);

    // v1: window path when rows match and x-window covers; else R13 gather
    const bool match = (y10 == y00) & (z10 == z00) &
                       ((unsigned)(x10 - x00) <= 2u);
    float o1;
    if (match) {
        float wy1b = iy1 - floorf(iy1), wy0b = 1.f - wy1b;
        float wz1b = iz1 - floorf(iz1), wz0b = 1.f - wz1b;
        // same rows as v0 -> same validity flags
        wy0b = ((unsigned)y00       < 128u) ? wy0b : 0.f;
        wy1b = ((unsigned)(y00 + 1) < 128u) ? wy1b : 0.f;
        wz0b = ((unsigned)z00       < 128u) ? wz0b : 0.f;
        wz1b = ((unsigned)(z00 + 1) < 128u) ? wz1b : 0.f;
        const f32x4 c1 = xweights(ix1, x10, xq);
        const float b00 = dot4(c1, W00), b01 = dot4(c1, W01);
        const float b10 = dot4(c1, W10), b11 = dot4(c1, W11);
        const float by0b = fmaf(wy1b, b01, wy0b * b00);
        const float by1b = fmaf(wy1b, b11, wy0b * b10);
        o1 = fmaf(wz1b, by1b, wz0b * by0b);
    } else {
        const Prep p1 = prep_s(ix1, iy1, iz1);
        f32x2 v1[4];
        #pragma unroll
        for (int j = 0; j < 4; ++j) v1[j] = bload2(r, p1.o[j]);
        o1 = blend_s(p1, v1);
    }

    f32x2 o; o.x = o0; o.y = o1;
    __builtin_nontemporal_store(o, (f32x2*)(x_reg + (size_t)b * INP) + i2);

    // R5-proven tail: wave shfl reduce -> LDS combine -> ONE store per block
    float acc = fmaf(o1, w2.y, o0 * w2.x);
    acc = wave_reduce(acc);
    __shared__ float sm[4];
    if ((threadIdx.x & 63) == 0) sm[threadIdx.x >> 6] = acc;
    __syncthreads();
    if (threadIdx.x == 0)
        partial[b * NBLK2 + blockIdx.x] = sm[0] + sm[1] + sm[2] + sm[3];
}

// ---------------------------------------------------------------------------
// K2 (fused reduce+outer, R13-proven): grid (128 chunks, 8 batches).
// ---------------------------------------------------------------------------
__global__ __launch_bounds__(256) void k_outer(
    const float* __restrict__ lnw, const float* __restrict__ partial,
    float* __restrict__ L)
{
    const int b   = blockIdx.y;
    const int tid = threadIdx.x;

    const f32x4* p4 = (const f32x4*)(partial + b * NBLK2);   // 512 f32x4
    const f32x4 a0 = p4[tid];
    const f32x4 a1 = p4[tid + 256];
    float v = (a0.x + a0.y) + (a0.z + a0.w) + (a1.x + a1.y) + (a1.z + a1.w);
    v = wave_reduce(v);
    __shared__ float sm[4];
    __shared__ float smt;
    if ((tid & 63) == 0) sm[tid >> 6] = v;
    __syncthreads();
    if (tid == 0) smt = (sm[0] + sm[1]) + (sm[2] + sm[3]);
    __syncthreads();
    const float sb = smt;

    const int base = blockIdx.x * 2048 + tid;    // f32x4 units within batch
    const f32x4* w4p = (const f32x4*)lnw;
    f32x4* L4 = (f32x4*)L + (size_t)b * (INP / 4);
    #pragma unroll
    for (int k = 0; k < 8; ++k) {
        const f32x4 w4 = w4p[base + k * 256];
        __builtin_nontemporal_store(sb * w4, L4 + base + k * 256);
    }
}

extern "C" void kernel_launch(void* const* d_in, const int* in_sizes, int n_in,
                              void* d_out, int out_size, void* d_ws, size_t ws_size,
                              hipStream_t stream) {
    const float* x       = (const float*)d_in[0];
    const int*   r_index = (const int*)d_in[1];
    const float* theta   = (const float*)d_in[2];
    const float* lnw     = (const float*)d_in[3];

    float* x_reg = (float*)d_out;
    float* L     = (float*)d_out + (size_t)NB * INP;

    float* partial = (float*)d_ws;            // 8*2048 floats = 64 KB

    dim3 grid1(NBLK2, NB);
    k_sample<<<grid1, 256, 0, stream>>>(x, r_index, theta, lnw, x_reg, partial);
    dim3 grid2(128, NB);
    k_outer<<<grid2, 256, 0, stream>>>(lnw, partial, L);
}

// Round 19
// 32.745 us; speedup vs baseline: 1.8127x; 1.0686x over previous
//
#include <hip/hip_runtime.h>

#define INP (128*128*64)   // 1048576
#define NB 8
#define NBLK4 1024         // k_sample blocks per batch: (INP/4)/256

typedef __attribute__((ext_vector_type(4))) float f32x4;
typedef __attribute__((ext_vector_type(2))) float f32x2;
typedef int v4i __attribute__((ext_vector_type(4)));

#if __has_builtin(__builtin_amdgcn_make_buffer_rsrc) && __has_builtin(__builtin_amdgcn_raw_buffer_load_b32)
#define RSRC_T __amdgpu_buffer_rsrc_t
__device__ __forceinline__ RSRC_T make_rsrc(const float* p) {
    return __builtin_amdgcn_make_buffer_rsrc((void*)p, (short)0, INP * 4, 0x00020000);
}
__device__ __forceinline__ float bload(RSRC_T r, int boff) {
    return __builtin_bit_cast(float, __builtin_amdgcn_raw_buffer_load_b32(r, boff, 0, 0));
}
#else
#define RSRC_T v4i
__device__ __forceinline__ RSRC_T make_rsrc(const float* p) {
    union { const float* p; unsigned u[2]; } pun; pun.p = p;
    RSRC_T r;
    r.x = (int)pun.u[0]; r.y = (int)pun.u[1]; r.z = INP * 4; r.w = 0x00020000;
    return r;
}
__device__ __forceinline__ float bload(RSRC_T r, int boff) {
    return __builtin_amdgcn_raw_buffer_load_f32(r, boff, 0, 0);
}
#endif

#if __has_builtin(__builtin_amdgcn_raw_buffer_load_b64)
__device__ __forceinline__ f32x2 bload2(RSRC_T r, int boff) {
    return __builtin_bit_cast(f32x2, __builtin_amdgcn_raw_buffer_load_b64(r, boff, 0, 0));
}
#else
__device__ __forceinline__ f32x2 bload2(RSRC_T r, int boff) {
    f32x2 v; v.x = bload(r, boff); v.y = bload(r, boff + 4); return v;
}
#endif

__device__ __forceinline__ float wave_reduce(float v) {
    #pragma unroll
    for (int off = 32; off > 0; off >>= 1) v += __shfl_down(v, off, 64);
    return v;
}

// R13-proven per-voxel prep: clamped always-in-bounds offsets + x-edges
// resolved in the weights. (R3/R7: never pair a possibly-negative SRSRC
// voffset with a folded imm.)
struct Prep {
    int o[4];
    float wa, wb, wy0, wy1, wz0, wz1;
};

__device__ __forceinline__ Prep prep_s(float ix, float iy, float iz) {
    const float fx = floorf(ix), fy = floorf(iy), fz = floorf(iz);
    const int x0 = (int)fx, y0 = (int)fy, z0 = (int)fz;
    const int x1 = x0 + 1,  y1 = y0 + 1,  z1 = z0 + 1;

    const float wx1 = ix - fx, wx0 = 1.f - wx1;
    Prep p;
    p.wy1 = iy - fy; p.wy0 = 1.f - p.wy1;
    p.wz1 = iz - fz; p.wz0 = 1.f - p.wz1;
    p.wy0 = ((unsigned)y0 < 128u) ? p.wy0 : 0.f;
    p.wy1 = ((unsigned)y1 < 128u) ? p.wy1 : 0.f;
    p.wz0 = ((unsigned)z0 < 128u) ? p.wz0 : 0.f;
    p.wz1 = ((unsigned)z1 < 128u) ? p.wz1 : 0.f;

    const float wx0z = ((unsigned)x0 < 64u) ? wx0 : 0.f;
    const float wx1z = ((unsigned)x1 < 64u) ? wx1 : 0.f;
    const bool hi = (x0 >= 63);
    const bool lo = (x0 < 0);
    p.wa = lo ? wx1z : (hi ? 0.f : wx0z);
    p.wb = hi ? wx0z : (lo ? 0.f : wx1z);

    const int yc0 = min(max(y0, 0), 127), yc1 = min(max(y1, 0), 127);
    const int zc0 = min(max(z0, 0), 127), zc1 = min(max(z1, 0), 127);
    const int xpb = min(max(x0, 0), 62) << 2;
    const int yb0 = (yc0 << 8) + xpb, yb1 = (yc1 << 8) + xpb;
    const int zb0 = zc0 << 15,        zb1 = zc1 << 15;
    p.o[0] = zb0 + yb0; p.o[1] = zb0 + yb1;
    p.o[2] = zb1 + yb0; p.o[3] = zb1 + yb1;
    return p;
}

__device__ __forceinline__ float blend_s(const Prep& p, const f32x2 v[4]) {
    const float bx00 = fmaf(p.wb, v[0].y, p.wa * v[0].x);
    const float bx01 = fmaf(p.wb, v[1].y, p.wa * v[1].x);
    const float bx10 = fmaf(p.wb, v[2].y, p.wa * v[2].x);
    const float bx11 = fmaf(p.wb, v[3].y, p.wa * v[3].x);
    const float by0  = fmaf(p.wy1, bx01, p.wy0 * bx00);
    const float by1  = fmaf(p.wy1, bx11, p.wy0 * bx10);
    return fmaf(p.wz1, by1, p.wz0 * by0);
}

// ---------------------------------------------------------------------------
// K1: one thread = FOUR x-consecutive voxels (lanes stay x-consecutive: a
// wave covers 4 full x-rows — same line footprint per voxel as R13). R9's
// 4-voxel failure was 4 sequential dependent sample rounds; here (R12 recipe)
// all 4 preps are computed, all 16 dwordx2 gathers issued, then 4 blends.
// Single matvec + delta coords (d/dw = t0, 2*t4, 2*t8 — R9-verified exact).
// One f32x4 NT store + f32x4 lnw load + one tail per 4 voxels.
// ---------------------------------------------------------------------------
__global__ __launch_bounds__(256) void k_sample(
    const float* __restrict__ x, const int* __restrict__ r_index,
    const float* __restrict__ theta, const float* __restrict__ lnw,
    float* __restrict__ x_reg, float* __restrict__ partial)
{
    const int b  = blockIdx.y;
    const int i4 = blockIdx.x * 256 + threadIdx.x;   // quad index
    const int w0 = (i4 & 15) << 2;                   // w of voxel 0
    const int h  = (i4 >> 4) & 127;
    const int d  = i4 >> 11;

    const f32x4 w4 = ((const f32x4*)lnw)[i4];        // issue early

    const float xs = fmaf((float)w0, 1.f/32.f, 1.f/64.f  - 1.f);
    const float ys = fmaf((float)h,  1.f/64.f, 1.f/128.f - 1.f);
    const float zs = fmaf((float)d,  1.f/64.f, 1.f/128.f - 1.f);

    const float* __restrict__ t = theta + r_index[b] * 12;   // uniform
    const float gx = fmaf(t[0], xs, fmaf(t[1], ys, fmaf(t[2],  zs, t[3])));
    const float gy = fmaf(t[4], xs, fmaf(t[5], ys, fmaf(t[6],  zs, t[7])));
    const float gz = fmaf(t[8], xs, fmaf(t[9], ys, fmaf(t[10], zs, t[11])));
    const float ix0 = fmaf(gx, 32.f, 31.5f);
    const float iy0 = fmaf(gy, 64.f, 63.5f);
    const float iz0 = fmaf(gz, 64.f, 63.5f);
    const float sx = t[0], sy = 2.f * t[4], sz = 2.f * t[8];

    // all 4 preps first (independent VALU chains)
    const Prep p0 = prep_s(ix0, iy0, iz0);
    const Prep p1 = prep_s(ix0 + sx, iy0 + sy, iz0 + sz);
    const Prep p2 = prep_s(fmaf(2.f, sx, ix0), fmaf(2.f, sy, iy0), fmaf(2.f, sz, iz0));
    const Prep p3 = prep_s(fmaf(3.f, sx, ix0), fmaf(3.f, sy, iy0), fmaf(3.f, sz, iz0));

    // all 16 gathers issued before any blend
    const RSRC_T r = make_rsrc(x + (size_t)b * INP);
    f32x2 v0[4], v1[4], v2[4], v3[4];
    #pragma unroll
    for (int j = 0; j < 4; ++j) v0[j] = bload2(r, p0.o[j]);
    #pragma unroll
    for (int j = 0; j < 4; ++j) v1[j] = bload2(r, p1.o[j]);
    #pragma unroll
    for (int j = 0; j < 4; ++j) v2[j] = bload2(r, p2.o[j]);
    #pragma unroll
    for (int j = 0; j < 4; ++j) v3[j] = bload2(r, p3.o[j]);

    const float o0 = blend_s(p0, v0);
    const float o1 = blend_s(p1, v1);
    const float o2 = blend_s(p2, v2);
    const float o3 = blend_s(p3, v3);

    f32x4 o; o.x = o0; o.y = o1; o.z = o2; o.w = o3;
    __builtin_nontemporal_store(o, (f32x4*)(x_reg + (size_t)b * INP) + i4);

    // R5-proven tail: wave shfl reduce -> LDS combine -> ONE store per block
    float acc = fmaf(o0, w4.x, o1 * w4.y) + fmaf(o2, w4.z, o3 * w4.w);
    acc = wave_reduce(acc);
    __shared__ float sm[4];
    if ((threadIdx.x & 63) == 0) sm[threadIdx.x >> 6] = acc;
    __syncthreads();
    if (threadIdx.x == 0)
        partial[b * NBLK4 + blockIdx.x] = sm[0] + sm[1] + sm[2] + sm[3];
}

// ---------------------------------------------------------------------------
// K2 (fused reduce+outer, R13-proven): grid (128 chunks, 8 batches). Each
// block redundantly reduces its batch's 1024 partials (1 f32x4/thread) then
// writes its 8192-float chunk of L[b] = s_b * lnw.
// ---------------------------------------------------------------------------
__global__ __launch_bounds__(256) void k_outer(
    const float* __restrict__ lnw, const float* __restrict__ partial,
    float* __restrict__ L)
{
    const int b   = blockIdx.y;
    const int tid = threadIdx.x;

    const f32x4* p4 = (const f32x4*)(partial + b * NBLK4);   // 256 f32x4
    const f32x4 a0 = p4[tid];
    float v = (a0.x + a0.y) + (a0.z + a0.w);
    v = wave_reduce(v);
    __shared__ float sm[4];
    __shared__ float smt;
    if ((tid & 63) == 0) sm[tid >> 6] = v;
    __syncthreads();
    if (tid == 0) smt = (sm[0] + sm[1]) + (sm[2] + sm[3]);
    __syncthreads();
    const float sb = smt;

    const int base = blockIdx.x * 2048 + tid;    // f32x4 units within batch
    const f32x4* w4p = (const f32x4*)lnw;
    f32x4* L4 = (f32x4*)L + (size_t)b * (INP / 4);
    #pragma unroll
    for (int k = 0; k < 8; ++k) {
        const f32x4 w4 = w4p[base + k * 256];
        __builtin_nontemporal_store(sb * w4, L4 + base + k * 256);
    }
}

extern "C" void kernel_launch(void* const* d_in, const int* in_sizes, int n_in,
                              void* d_out, int out_size, void* d_ws, size_t ws_size,
                              hipStream_t stream) {
    const float* x       = (const float*)d_in[0];
    const int*   r_index = (const int*)d_in[1];
    const float* theta   = (const float*)d_in[2];
    const float* lnw     = (const float*)d_in[3];

    float* x_reg = (float*)d_out;
    float* L     = (float*)d_out + (size_t)NB * INP;

    float* partial = (float*)d_ws;            // 8*1024 floats = 32 KB

    dim3 grid1(NBLK4, NB);
    k_sample<<<grid1, 256, 0, stream>>>(x, r_index, theta, lnw, x_reg, partial);
    dim3 grid2(128, NB);
    k_outer<<<grid2, 256, 0, stream>>>(lnw, partial, L);
}